// Round 4
// baseline (492.109 us; speedup 1.0000x reference)
//
#include <hip/hip_runtime.h>
#include <math.h>

#define D 64
#define BN_EPS 1e-5f
#define CH 160   // edges per chunk: even, multiple of 16

static __device__ __forceinline__ unsigned short f2bf(float f) {
    unsigned int u = __float_as_uint(f);
    unsigned int r = (u + 0x7fffu + ((u >> 16) & 1u)) >> 16;
    return (unsigned short)r;
}
static __device__ __forceinline__ float clamp60(float x) {
    return fminf(fmaxf(x, -60.f), 60.f);
}

// ---------------- fused 4-GEMM ----------------
// EK = exp(-clamp(x@Wk+bk)) f32; QV = u32 {bf16(v)<<16 | bf16(exp(-clamp(q)))};
// AGG = x@Ws+bs+bias. If APPLY_BN: normalize input with stats[128..255] while staging.
template<bool APPLY_BN>
__global__ __launch_bounds__(256) void gemm_fused(
    const float* x,                       // may alias AGG (own rows only)
    const float* __restrict__ Wk, const float* __restrict__ bk,
    const float* __restrict__ Wq, const float* __restrict__ bq,
    const float* __restrict__ Wv, const float* __restrict__ bv,
    const float* __restrict__ Ws, const float* __restrict__ bs,
    const float* __restrict__ bias, const float* __restrict__ stats,
    float* __restrict__ EK, unsigned int* __restrict__ QV,
    float* AGG, int nrows)
{
    __shared__ float xt[64 * D];
    const int t = threadIdx.x;
    const int row0 = blockIdx.x * 64;

    #pragma unroll
    for (int i = 0; i < 4; ++i) {
        int fidx = t + i * 256;
        int r = fidx >> 4;
        int c4 = fidx & 15;
        int grow = row0 + r;
        float4 v = make_float4(0.f, 0.f, 0.f, 0.f);
        if (grow < nrows)
            v = *reinterpret_cast<const float4*>(&x[(size_t)grow * D + c4 * 4]);
        if (APPLY_BN) {
            const float4* st4 = reinterpret_cast<const float4*>(stats);
            float4 sc = st4[32 + c4];
            float4 sh = st4[48 + c4];
            v.x = v.x * sc.x + sh.x;
            v.y = v.y * sc.y + sh.y;
            v.z = v.z * sc.z + sh.z;
            v.w = v.w * sc.w + sh.w;
        }
        *reinterpret_cast<float4*>(&xt[fidx * 4]) = v;
    }
    __syncthreads();

    const int c  = t & 63;
    const int rg = t >> 6;

    float aK[16], aQ[16], aV[16], aS[16];
    #pragma unroll
    for (int r = 0; r < 16; ++r) { aK[r] = 0.f; aQ[r] = 0.f; aV[r] = 0.f; aS[r] = 0.f; }

    for (int k4 = 0; k4 < 16; ++k4) {
        float wk[4], wq[4], wv[4], wsv[4];
        #pragma unroll
        for (int j = 0; j < 4; ++j) {
            int kk = k4 * 4 + j;
            wk[j]  = Wk[kk * D + c];
            wq[j]  = Wq[kk * D + c];
            wv[j]  = Wv[kk * D + c];
            wsv[j] = Ws[kk * D + c];
        }
        #pragma unroll
        for (int r = 0; r < 16; ++r) {
            float4 xv = *reinterpret_cast<const float4*>(&xt[(rg * 16 + r) * D + k4 * 4]);
            aK[r] = fmaf(xv.x, wk[0],  fmaf(xv.y, wk[1],  fmaf(xv.z, wk[2],  fmaf(xv.w, wk[3],  aK[r]))));
            aQ[r] = fmaf(xv.x, wq[0],  fmaf(xv.y, wq[1],  fmaf(xv.z, wq[2],  fmaf(xv.w, wq[3],  aQ[r]))));
            aV[r] = fmaf(xv.x, wv[0],  fmaf(xv.y, wv[1],  fmaf(xv.z, wv[2],  fmaf(xv.w, wv[3],  aV[r]))));
            aS[r] = fmaf(xv.x, wsv[0], fmaf(xv.y, wsv[1], fmaf(xv.z, wsv[2], fmaf(xv.w, wsv[3], aS[r]))));
        }
    }

    const float bkc = bk[c], bqc = bq[c], bvc = bv[c], bsc = bs[c] + bias[c];
    #pragma unroll
    for (int r = 0; r < 16; ++r) {
        int grow = row0 + rg * 16 + r;
        if (grow < nrows) {
            size_t o = (size_t)grow * D + c;
            EK[o] = __expf(-clamp60(aK[r] + bkc));
            float eq = __expf(-clamp60(aQ[r] + bqc));
            QV[o] = ((unsigned int)f2bf(aV[r] + bvc) << 16) | (unsigned int)f2bf(eq);
            AGG[o] = aS[r] + bsc;
        }
    }
}

// ---------------- CSR build (degree padded to even) ----------------
__global__ __launch_bounds__(256) void hist_kernel(const int* __restrict__ dst,
                                                   int* __restrict__ counts, int nedges)
{
    int i = blockIdx.x * 256 + threadIdx.x;
    if (i < nedges) atomicAdd(&counts[dst[i]], 1);
}

__global__ __launch_bounds__(256) void scan1(const int* __restrict__ counts,
                                             int* __restrict__ offs,
                                             int* __restrict__ bsums, int n)
{
    __shared__ int tmp[256];
    const int t = threadIdx.x;
    const int i = blockIdx.x * 256 + t;
    int v = (i < n) ? ((counts[i] + 1) & ~1) : 0;   // padded-to-even degree
    tmp[t] = v;
    __syncthreads();
    for (int off = 1; off < 256; off <<= 1) {
        int add = (t >= off) ? tmp[t - off] : 0;
        __syncthreads();
        tmp[t] += add;
        __syncthreads();
    }
    if (i < n) offs[i] = tmp[t] - v;   // exclusive
    if (t == 255) bsums[blockIdx.x] = tmp[255];
}

__global__ __launch_bounds__(512) void scan2(int* __restrict__ bsums, int nb)
{
    __shared__ int tmp[512];
    const int t = threadIdx.x;
    int v = (t < nb) ? bsums[t] : 0;
    tmp[t] = v;
    __syncthreads();
    for (int off = 1; off < 512; off <<= 1) {
        int add = (t >= off) ? tmp[t - off] : 0;
        __syncthreads();
        tmp[t] += add;
        __syncthreads();
    }
    if (t < nb) bsums[t] = tmp[t] - v;
}

__global__ __launch_bounds__(256) void scan3(int* __restrict__ offs,
                                             const int* __restrict__ bsums,
                                             int* __restrict__ cursor,
                                             const int* __restrict__ counts,
                                             float* __restrict__ stats,
                                             unsigned int* __restrict__ QV, int n)
{
    int i = blockIdx.x * 256 + threadIdx.x;
    if (i < n) {
        int o = offs[i] + bsums[blockIdx.x];
        offs[i] = o;
        cursor[i] = o;
        if (i == n - 1) offs[n] = o + ((counts[i] + 1) & ~1);  // padded total
    }
    if (i < 128) stats[i] = 0.f;                       // BN accumulators for layer 1
    if (i < 64)  QV[((size_t)n << 6) | i] = 0x00003F80u;  // dummy row: v=0, eq=1.0
}

__global__ __launch_bounds__(256) void scatter_kernel(const int* __restrict__ src,
                                                      const int* __restrict__ dst,
                                                      int* __restrict__ cursor,
                                                      int* __restrict__ csr_src, int nedges)
{
    int i = blockIdx.x * 256 + threadIdx.x;
    if (i < nedges) {
        int d = dst[i];
        int pos = atomicAdd(&cursor[d], 1);
        csr_src[pos] = src[i];
    }
}

__global__ __launch_bounds__(256) void pad_fill(const int* __restrict__ counts,
                                                const int* __restrict__ offs,
                                                int* __restrict__ csr_src, int n)
{
    int i = blockIdx.x * 256 + threadIdx.x;
    if (i < n && (counts[i] & 1)) csr_src[offs[i] + counts[i]] = n;  // dummy src
}

__global__ __launch_bounds__(256) void node_start_k(const int* __restrict__ offs,
                                                    int* __restrict__ node_start, int n)
{
    int i = blockIdx.x * 256 + threadIdx.x;
    if (i >= n) return;
    int a = offs[i], b = offs[i + 1];
    if (a == b) return;
    for (int c = (a + CH - 1) / CH; c * CH < b; ++c) node_start[c] = i;
}

// ---------------- edge-parallel aggregation over CSR chunks ----------------
// EPI = edges per load instruction (1: dword/lane/row; 2: dwordx2/lane, half-wave pairs).
// Interior nodes: non-atomic RMW (exclusive). Boundary nodes: atomicAdd partials.
template<int EPI>
__global__ __launch_bounds__(256) void edge_agg(
    const int* __restrict__ csr_src, const int* __restrict__ offs,
    const int* __restrict__ node_start,
    const float* __restrict__ EK, const unsigned int* __restrict__ QV,
    float* __restrict__ AGG, int nnodes)
{
    const int lane  = threadIdx.x & 63;
    const int chunk = __builtin_amdgcn_readfirstlane((int)((blockIdx.x * 256 + threadIdx.x) >> 6));
    const int Epad  = offs[nnodes];
    const int e0 = chunk * CH;
    if (e0 >= Epad) return;
    const int e1 = min(e0 + CH, Epad);

    int n      = node_start[chunk];
    int nstart = offs[n];
    int nend   = offs[n + 1];

    float accx = 0.f, accy = 0.f;
    float ekx = 0.f, eky = 0.f;
    if (EPI == 2) {
        float2 ekv = reinterpret_cast<const float2*>(EK)[((size_t)n << 5) | (lane & 31)];
        ekx = ekv.x; eky = ekv.y;
    } else {
        ekx = EK[((size_t)n << 6) | lane];
    }

    auto flush = [&](bool partial) {
        if (EPI == 2) {
            float tx = accx + __shfl_xor(accx, 32);
            float ty = accy + __shfl_xor(accy, 32);
            if (lane < 32) {
                int base = (n << 6) + (lane << 1);
                if (partial) {
                    atomicAdd(&AGG[base], tx);
                    atomicAdd(&AGG[base + 1], ty);
                } else {
                    float2* r = reinterpret_cast<float2*>(&AGG[base]);
                    float2 cur = *r;
                    cur.x += tx; cur.y += ty;
                    *r = cur;
                }
            }
        } else {
            int idx = (n << 6) | lane;
            if (partial) atomicAdd(&AGG[idx], accx);
            else         AGG[idx] += accx;
        }
    };
    auto advance = [&](int eidx) {
        do { ++n; } while (offs[n + 1] == eidx);   // skip empty nodes
        nstart = eidx;
        nend   = offs[n + 1];
        accx = 0.f; accy = 0.f;
        if (EPI == 2) {
            float2 ekv = reinterpret_cast<const float2*>(EK)[((size_t)n << 5) | (lane & 31)];
            ekx = ekv.x; eky = ekv.y;
        } else {
            ekx = EK[((size_t)n << 6) | lane];
        }
    };

    for (int e = e0; e < e1; e += 64) {
        const int cnt = min(64, e1 - e);
        int sAll = (lane < cnt) ? csr_src[e + lane] : nnodes;
        for (int b = 0; b < cnt; b += 16) {
            const int bc = min(16, cnt - b);
            if (EPI == 1) {
                unsigned int p[16];
                #pragma unroll
                for (int u = 0; u < 16; ++u) {
                    if (u < bc) {
                        int s = __shfl(sAll, b + u);
                        p[u] = QV[((size_t)s << 6) | lane];
                    }
                }
                #pragma unroll
                for (int u = 0; u < 16; ++u) {
                    if (u < bc) {
                        int eidx = e + b + u;
                        if (eidx == nend) { flush(nstart < e0); advance(eidx); }
                        float eq = __uint_as_float(p[u] << 16);
                        float vv = __uint_as_float(p[u] & 0xffff0000u);
                        float g  = __builtin_amdgcn_rcpf(fmaf(ekx, eq, 1.0f));
                        accx = fmaf(g, vv, accx);
                    }
                }
            } else {
                unsigned long long p[8];
                const int half = lane >> 5;
                #pragma unroll
                for (int u = 0; u < 8; ++u) {
                    if (2 * u < bc) {
                        int s = __shfl(sAll, b + 2 * u + half);
                        p[u] = reinterpret_cast<const unsigned long long*>(QV)[((size_t)s << 5) | (lane & 31)];
                    }
                }
                #pragma unroll
                for (int u = 0; u < 8; ++u) {
                    if (2 * u < bc) {
                        int eidx = e + b + 2 * u;
                        if (eidx == nend) { flush(nstart < e0); advance(eidx); }
                        unsigned int lo = (unsigned int)p[u];
                        unsigned int hi = (unsigned int)(p[u] >> 32);
                        float eq0 = __uint_as_float(lo << 16);
                        float v0  = __uint_as_float(lo & 0xffff0000u);
                        float eq1 = __uint_as_float(hi << 16);
                        float v1  = __uint_as_float(hi & 0xffff0000u);
                        float g0  = __builtin_amdgcn_rcpf(fmaf(ekx, eq0, 1.0f));
                        float g1  = __builtin_amdgcn_rcpf(fmaf(eky, eq1, 1.0f));
                        accx = fmaf(g0, v0, accx);
                        accy = fmaf(g1, v1, accy);
                    }
                }
            }
        }
    }
    flush((nstart < e0) || (nend > e1));
}

// ---------------- ReLU (in place) + per-feature BN stats ----------------
__global__ __launch_bounds__(256) void relu_stats(
    float* __restrict__ AGG, float* __restrict__ stats, int n4)
{
    __shared__ float ls[128];
    const int t = threadIdx.x;
    if (t < 128) ls[t] = 0.f;
    __syncthreads();
    int idx = blockIdx.x * 256 + t;
    const int stride = gridDim.x * 256;
    const int f0 = (idx << 2) & 63;     // invariant: stride*4 % 64 == 0
    float s0=0,s1=0,s2=0,s3=0,q0=0,q1=0,q2=0,q3=0;
    for (; idx < n4; idx += stride) {
        float4 a = reinterpret_cast<float4*>(AGG)[idx];
        a.x = fmaxf(a.x, 0.f); a.y = fmaxf(a.y, 0.f);
        a.z = fmaxf(a.z, 0.f); a.w = fmaxf(a.w, 0.f);
        reinterpret_cast<float4*>(AGG)[idx] = a;
        s0 += a.x; q0 = fmaf(a.x, a.x, q0);
        s1 += a.y; q1 = fmaf(a.y, a.y, q1);
        s2 += a.z; q2 = fmaf(a.z, a.z, q2);
        s3 += a.w; q3 = fmaf(a.w, a.w, q3);
    }
    atomicAdd(&ls[f0],     s0); atomicAdd(&ls[f0 + 1],     s1);
    atomicAdd(&ls[f0 + 2], s2); atomicAdd(&ls[f0 + 3],     s3);
    atomicAdd(&ls[64 + f0],     q0); atomicAdd(&ls[64 + f0 + 1], q1);
    atomicAdd(&ls[64 + f0 + 2], q2); atomicAdd(&ls[64 + f0 + 3], q3);
    __syncthreads();
    if (t < 128) atomicAdd(&stats[t], ls[t]);
}

// ---------------- finalize: scale/shift; re-zero sums for next layer ----------------
__global__ void finalize_stats(float* __restrict__ stats,
                               const float* __restrict__ gamma,
                               const float* __restrict__ beta, int nrows)
{
    int t = threadIdx.x;  // 64 threads
    float invN = 1.0f / (float)nrows;
    float mean = stats[t] * invN;
    float var  = stats[64 + t] * invN - mean * mean;
    float sc   = gamma[t] * rsqrtf(var + BN_EPS);
    stats[128 + t] = sc;
    stats[192 + t] = beta[t] - mean * sc;
    stats[t] = 0.f;
    stats[64 + t] = 0.f;
}

// ---------------- apply (final layer): out = y*scale + shift ----------------
__global__ __launch_bounds__(256) void apply_bn(
    const float* __restrict__ AGG, const float* __restrict__ stats,
    float* __restrict__ xout, int ntot4)
{
    int idx = blockIdx.x * 256 + threadIdx.x;
    const int stride = gridDim.x * 256;
    const float4* st4 = reinterpret_cast<const float4*>(stats);
    for (; idx < ntot4; idx += stride) {
        float4 a = reinterpret_cast<const float4*>(AGG)[idx];
        int c4 = idx & 15;
        float4 sc = st4[32 + c4];
        float4 sh = st4[48 + c4];
        float4 o;
        o.x = a.x * sc.x + sh.x;
        o.y = a.y * sc.y + sh.y;
        o.z = a.z * sc.z + sh.z;
        o.w = a.w * sc.w + sh.w;
        reinterpret_cast<float4*>(xout)[idx] = o;
    }
}

extern "C" void kernel_launch(void* const* d_in, const int* in_sizes, int n_in,
                              void* d_out, int out_size, void* d_ws, size_t ws_size,
                              hipStream_t stream)
{
    const float* x     = (const float*)d_in[0];
    const int*   ei    = (const int*)d_in[1];
    const float* Wk    = (const float*)d_in[3];
    const float* bk    = (const float*)d_in[4];
    const float* Wq    = (const float*)d_in[5];
    const float* bq    = (const float*)d_in[6];
    const float* Wv    = (const float*)d_in[7];
    const float* bv    = (const float*)d_in[8];
    const float* Ws    = (const float*)d_in[9];
    const float* bs    = (const float*)d_in[10];
    const float* bias  = (const float*)d_in[11];
    const float* gamma = (const float*)d_in[12];
    const float* beta  = (const float*)d_in[13];

    const int nrows  = in_sizes[0] / D;     // 100000
    const int nedges = in_sizes[1] / 2;     // 1250000
    const int nm     = nrows * D;
    const int NCmax  = (nedges + nrows + CH - 1) / CH;

    float* out = (float*)d_out;
    float* ws  = (float*)d_ws;
    float* EK  = ws;                                     // nm f32
    unsigned int* QV = (unsigned int*)(EK + nm);         // nm + 64 u32 (incl. dummy row)
    float* AGG = (float*)(QV + nm + 64);                 // nm f32
    float* stats = AGG + nm;                             // 256 f32
    int* counts  = (int*)(stats + 256);                  // nrows
    int* offs    = counts + nrows;                       // nrows+1
    int* cursor  = offs + nrows + 1;                     // nrows
    int* bsums   = cursor + nrows;                       // 512
    int* nstart_map = bsums + 512;                       // NCmax
    int* csr_src = nstart_map + NCmax;                   // nedges + nrows (padded)

    const int* srcI = ei;
    const int* dstI = ei + nedges;

    const int gemm_blocks = (nrows + 63) / 64;
    const int edge_blocks = (nedges + 255) / 256;
    const int node_blocks = (nrows + 255) / 256;         // 391 (<512 for scan2)
    const int agg_blocks  = (NCmax + 3) / 4;             // 1 wave per chunk

    // ---- CSR build (even-padded; identical for both layers) ----
    hipMemsetAsync(counts, 0, (size_t)nrows * sizeof(int), stream);
    hist_kernel<<<edge_blocks, 256, 0, stream>>>(dstI, counts, nedges);
    scan1<<<node_blocks, 256, 0, stream>>>(counts, offs, bsums, nrows);
    scan2<<<1, 512, 0, stream>>>(bsums, node_blocks);
    scan3<<<node_blocks, 256, 0, stream>>>(offs, bsums, cursor, counts, stats, QV, nrows);
    scatter_kernel<<<edge_blocks, 256, 0, stream>>>(srcI, dstI, cursor, csr_src, nedges);
    pad_fill<<<node_blocks, 256, 0, stream>>>(counts, offs, csr_src, nrows);
    node_start_k<<<node_blocks, 256, 0, stream>>>(offs, nstart_map, nrows);

    // ---- layer 1 (variant A: 2 edges / load inst) ----
    gemm_fused<false><<<gemm_blocks, 256, 0, stream>>>(x,
        Wk, bk, Wq, bq, Wv, bv, Ws, bs, bias, stats, EK, QV, AGG, nrows);
    edge_agg<2><<<agg_blocks, 256, 0, stream>>>(csr_src, offs, nstart_map, EK, QV, AGG, nrows);
    relu_stats<<<1024, 256, 0, stream>>>(AGG, stats, nm / 4);
    finalize_stats<<<1, 64, 0, stream>>>(stats, gamma, beta, nrows);

    // ---- layer 2 (variant B: 1 edge / load inst; BN-apply fused into staging) ----
    gemm_fused<true><<<gemm_blocks, 256, 0, stream>>>(AGG,
        Wk + D * D, bk + D, Wq + D * D, bq + D, Wv + D * D, bv + D,
        Ws + D * D, bs + D, bias + D, stats, EK, QV, AGG, nrows);
    edge_agg<1><<<agg_blocks, 256, 0, stream>>>(csr_src, offs, nstart_map, EK, QV, AGG, nrows);
    relu_stats<<<1024, 256, 0, stream>>>(AGG, stats, nm / 4);
    finalize_stats<<<1, 64, 0, stream>>>(stats, gamma + D, beta + D, nrows);
    apply_bn<<<2048, 256, 0, stream>>>(AGG, stats, out, nm / 4);
}

// Round 5
// 423.510 us; speedup vs baseline: 1.1620x; 1.1620x over previous
//
#include <hip/hip_runtime.h>
#include <math.h>

#define D 64
#define BN_EPS 1e-5f
#define CH 160   // edges per chunk: even, multiple of 16

static __device__ __forceinline__ unsigned short f2bf(float f) {
    unsigned int u = __float_as_uint(f);
    unsigned int r = (u + 0x7fffu + ((u >> 16) & 1u)) >> 16;
    return (unsigned short)r;
}
static __device__ __forceinline__ float clamp60(float x) {
    return fminf(fmaxf(x, -60.f), 60.f);
}

// ---------------- fused 4-GEMM ----------------
// EK = exp(-clamp(x@Wk+bk)) f32; QV = u32 {bf16(v)<<16 | bf16(exp(-clamp(q)))};
// AGG = x@Ws+bs+bias. If APPLY_BN: normalize input with stats[128..255] while staging.
template<bool APPLY_BN>
__global__ __launch_bounds__(256) void gemm_fused(
    const float* x,                       // may alias AGG (own rows only)
    const float* __restrict__ Wk, const float* __restrict__ bk,
    const float* __restrict__ Wq, const float* __restrict__ bq,
    const float* __restrict__ Wv, const float* __restrict__ bv,
    const float* __restrict__ Ws, const float* __restrict__ bs,
    const float* __restrict__ bias, const float* __restrict__ stats,
    float* __restrict__ EK, unsigned int* __restrict__ QV,
    float* AGG, int nrows)
{
    __shared__ float xt[64 * D];
    const int t = threadIdx.x;
    const int row0 = blockIdx.x * 64;

    #pragma unroll
    for (int i = 0; i < 4; ++i) {
        int fidx = t + i * 256;
        int r = fidx >> 4;
        int c4 = fidx & 15;
        int grow = row0 + r;
        float4 v = make_float4(0.f, 0.f, 0.f, 0.f);
        if (grow < nrows)
            v = *reinterpret_cast<const float4*>(&x[(size_t)grow * D + c4 * 4]);
        if (APPLY_BN) {
            const float4* st4 = reinterpret_cast<const float4*>(stats);
            float4 sc = st4[32 + c4];
            float4 sh = st4[48 + c4];
            v.x = v.x * sc.x + sh.x;
            v.y = v.y * sc.y + sh.y;
            v.z = v.z * sc.z + sh.z;
            v.w = v.w * sc.w + sh.w;
        }
        *reinterpret_cast<float4*>(&xt[fidx * 4]) = v;
    }
    __syncthreads();

    const int c  = t & 63;
    const int rg = t >> 6;

    float aK[16], aQ[16], aV[16], aS[16];
    #pragma unroll
    for (int r = 0; r < 16; ++r) { aK[r] = 0.f; aQ[r] = 0.f; aV[r] = 0.f; aS[r] = 0.f; }

    for (int k4 = 0; k4 < 16; ++k4) {
        float wk[4], wq[4], wv[4], wsv[4];
        #pragma unroll
        for (int j = 0; j < 4; ++j) {
            int kk = k4 * 4 + j;
            wk[j]  = Wk[kk * D + c];
            wq[j]  = Wq[kk * D + c];
            wv[j]  = Wv[kk * D + c];
            wsv[j] = Ws[kk * D + c];
        }
        #pragma unroll
        for (int r = 0; r < 16; ++r) {
            float4 xv = *reinterpret_cast<const float4*>(&xt[(rg * 16 + r) * D + k4 * 4]);
            aK[r] = fmaf(xv.x, wk[0],  fmaf(xv.y, wk[1],  fmaf(xv.z, wk[2],  fmaf(xv.w, wk[3],  aK[r]))));
            aQ[r] = fmaf(xv.x, wq[0],  fmaf(xv.y, wq[1],  fmaf(xv.z, wq[2],  fmaf(xv.w, wq[3],  aQ[r]))));
            aV[r] = fmaf(xv.x, wv[0],  fmaf(xv.y, wv[1],  fmaf(xv.z, wv[2],  fmaf(xv.w, wv[3],  aV[r]))));
            aS[r] = fmaf(xv.x, wsv[0], fmaf(xv.y, wsv[1], fmaf(xv.z, wsv[2], fmaf(xv.w, wsv[3], aS[r]))));
        }
    }

    const float bkc = bk[c], bqc = bq[c], bvc = bv[c], bsc = bs[c] + bias[c];
    #pragma unroll
    for (int r = 0; r < 16; ++r) {
        int grow = row0 + rg * 16 + r;
        if (grow < nrows) {
            size_t o = (size_t)grow * D + c;
            EK[o] = __expf(-clamp60(aK[r] + bkc));
            float eq = __expf(-clamp60(aQ[r] + bqc));
            QV[o] = ((unsigned int)f2bf(aV[r] + bvc) << 16) | (unsigned int)f2bf(eq);
            AGG[o] = aS[r] + bsc;
        }
    }
}

// ---------------- CSR build (degree padded to even) ----------------
// Histogram; the atomic's return value IS this edge's rank within its dst bucket.
__global__ __launch_bounds__(256) void hist_rank(const int* __restrict__ dst,
                                                 int* __restrict__ counts,
                                                 int* __restrict__ rank, int nedges)
{
    int i = blockIdx.x * 256 + threadIdx.x;
    if (i < nedges) {
        int r = atomicAdd(&counts[dst[i]], 1);
        rank[i] = r;
    }
}

__global__ __launch_bounds__(256) void scan1(const int* __restrict__ counts,
                                             int* __restrict__ offs,
                                             int* __restrict__ bsums, int n)
{
    __shared__ int tmp[256];
    const int t = threadIdx.x;
    const int i = blockIdx.x * 256 + t;
    int v = (i < n) ? ((counts[i] + 1) & ~1) : 0;   // padded-to-even degree
    tmp[t] = v;
    __syncthreads();
    for (int off = 1; off < 256; off <<= 1) {
        int add = (t >= off) ? tmp[t - off] : 0;
        __syncthreads();
        tmp[t] += add;
        __syncthreads();
    }
    if (i < n) offs[i] = tmp[t] - v;   // exclusive
    if (t == 255) bsums[blockIdx.x] = tmp[255];
}

__global__ __launch_bounds__(512) void scan2(int* __restrict__ bsums, int nb)
{
    __shared__ int tmp[512];
    const int t = threadIdx.x;
    int v = (t < nb) ? bsums[t] : 0;
    tmp[t] = v;
    __syncthreads();
    for (int off = 1; off < 512; off <<= 1) {
        int add = (t >= off) ? tmp[t - off] : 0;
        __syncthreads();
        tmp[t] += add;
        __syncthreads();
    }
    if (t < nb) bsums[t] = tmp[t] - v;
}

__global__ __launch_bounds__(256) void scan3(int* __restrict__ offs,
                                             const int* __restrict__ bsums,
                                             const int* __restrict__ counts,
                                             float* __restrict__ stats,
                                             unsigned int* __restrict__ QV, int n)
{
    int i = blockIdx.x * 256 + threadIdx.x;
    if (i < n) {
        int o = offs[i] + bsums[blockIdx.x];
        offs[i] = o;
        if (i == n - 1) offs[n] = o + ((counts[i] + 1) & ~1);  // padded total
    }
    if (i < 128) stats[i] = 0.f;                       // BN accumulators for layer 1
    if (i < 64)  QV[((size_t)n << 6) | i] = 0x00003F80u;  // dummy row: v=0, eq=1.0
}

// position = offs[dst] + rank  -> plain random store, no atomic, no return dependency
__global__ __launch_bounds__(256) void scatter_norank(const int* __restrict__ src,
                                                      const int* __restrict__ dst,
                                                      const int* __restrict__ offs,
                                                      const int* __restrict__ rank,
                                                      int* __restrict__ csr_src, int nedges)
{
    int i = blockIdx.x * 256 + threadIdx.x;
    if (i < nedges) {
        int d = dst[i];
        csr_src[offs[d] + rank[i]] = src[i];
    }
}

__global__ __launch_bounds__(256) void pad_fill(const int* __restrict__ counts,
                                                const int* __restrict__ offs,
                                                int* __restrict__ csr_src, int n)
{
    int i = blockIdx.x * 256 + threadIdx.x;
    if (i < n && (counts[i] & 1)) csr_src[offs[i] + counts[i]] = n;  // dummy src
}

__global__ __launch_bounds__(256) void node_start_k(const int* __restrict__ offs,
                                                    int* __restrict__ node_start, int n)
{
    int i = blockIdx.x * 256 + threadIdx.x;
    if (i >= n) return;
    int a = offs[i], b = offs[i + 1];
    if (a == b) return;
    for (int c = (a + CH - 1) / CH; c * CH < b; ++c) node_start[c] = i;
}

// ---------------- edge-parallel aggregation over CSR chunks ----------------
// EPI = edges per load instruction (1: dword/lane/row; 2: dwordx2/lane, half-wave pairs).
// Interior nodes: non-atomic RMW (exclusive). Boundary nodes: atomicAdd partials.
template<int EPI>
__global__ __launch_bounds__(256) void edge_agg(
    const int* __restrict__ csr_src, const int* __restrict__ offs,
    const int* __restrict__ node_start,
    const float* __restrict__ EK, const unsigned int* __restrict__ QV,
    float* __restrict__ AGG, int nnodes)
{
    const int lane  = threadIdx.x & 63;
    const int chunk = __builtin_amdgcn_readfirstlane((int)((blockIdx.x * 256 + threadIdx.x) >> 6));
    const int Epad  = offs[nnodes];
    const int e0 = chunk * CH;
    if (e0 >= Epad) return;
    const int e1 = min(e0 + CH, Epad);

    int n      = node_start[chunk];
    int nstart = offs[n];
    int nend   = offs[n + 1];

    float accx = 0.f, accy = 0.f;
    float ekx = 0.f, eky = 0.f;
    if (EPI == 2) {
        float2 ekv = reinterpret_cast<const float2*>(EK)[((size_t)n << 5) | (lane & 31)];
        ekx = ekv.x; eky = ekv.y;
    } else {
        ekx = EK[((size_t)n << 6) | lane];
    }

    auto flush = [&](bool partial) {
        if (EPI == 2) {
            float tx = accx + __shfl_xor(accx, 32);
            float ty = accy + __shfl_xor(accy, 32);
            if (lane < 32) {
                int base = (n << 6) + (lane << 1);
                if (partial) {
                    atomicAdd(&AGG[base], tx);
                    atomicAdd(&AGG[base + 1], ty);
                } else {
                    float2* r = reinterpret_cast<float2*>(&AGG[base]);
                    float2 cur = *r;
                    cur.x += tx; cur.y += ty;
                    *r = cur;
                }
            }
        } else {
            int idx = (n << 6) | lane;
            if (partial) atomicAdd(&AGG[idx], accx);
            else         AGG[idx] += accx;
        }
    };
    auto advance = [&](int eidx) {
        do { ++n; } while (offs[n + 1] == eidx);   // skip empty nodes
        nstart = eidx;
        nend   = offs[n + 1];
        accx = 0.f; accy = 0.f;
        if (EPI == 2) {
            float2 ekv = reinterpret_cast<const float2*>(EK)[((size_t)n << 5) | (lane & 31)];
            ekx = ekv.x; eky = ekv.y;
        } else {
            ekx = EK[((size_t)n << 6) | lane];
        }
    };

    for (int e = e0; e < e1; e += 64) {
        const int cnt = min(64, e1 - e);
        int sAll = (lane < cnt) ? csr_src[e + lane] : nnodes;
        for (int b = 0; b < cnt; b += 16) {
            const int bc = min(16, cnt - b);
            if (EPI == 1) {
                unsigned int p[16];
                #pragma unroll
                for (int u = 0; u < 16; ++u) {
                    if (u < bc) {
                        int s = __shfl(sAll, b + u);
                        p[u] = QV[((size_t)s << 6) | lane];
                    }
                }
                #pragma unroll
                for (int u = 0; u < 16; ++u) {
                    if (u < bc) {
                        int eidx = e + b + u;
                        if (eidx == nend) { flush(nstart < e0); advance(eidx); }
                        float eq = __uint_as_float(p[u] << 16);
                        float vv = __uint_as_float(p[u] & 0xffff0000u);
                        float g  = __builtin_amdgcn_rcpf(fmaf(ekx, eq, 1.0f));
                        accx = fmaf(g, vv, accx);
                    }
                }
            } else {
                unsigned long long p[8];
                const int half = lane >> 5;
                #pragma unroll
                for (int u = 0; u < 8; ++u) {
                    if (2 * u < bc) {
                        int s = __shfl(sAll, b + 2 * u + half);
                        p[u] = reinterpret_cast<const unsigned long long*>(QV)[((size_t)s << 5) | (lane & 31)];
                    }
                }
                #pragma unroll
                for (int u = 0; u < 8; ++u) {
                    if (2 * u < bc) {
                        int eidx = e + b + 2 * u;
                        if (eidx == nend) { flush(nstart < e0); advance(eidx); }
                        unsigned int lo = (unsigned int)p[u];
                        unsigned int hi = (unsigned int)(p[u] >> 32);
                        float eq0 = __uint_as_float(lo << 16);
                        float v0  = __uint_as_float(lo & 0xffff0000u);
                        float eq1 = __uint_as_float(hi << 16);
                        float v1  = __uint_as_float(hi & 0xffff0000u);
                        float g0  = __builtin_amdgcn_rcpf(fmaf(ekx, eq0, 1.0f));
                        float g1  = __builtin_amdgcn_rcpf(fmaf(eky, eq1, 1.0f));
                        accx = fmaf(g0, v0, accx);
                        accy = fmaf(g1, v1, accy);
                    }
                }
            }
        }
    }
    flush((nstart < e0) || (nend > e1));
}

// ---------------- ReLU (in place) + per-feature BN stats ----------------
__global__ __launch_bounds__(256) void relu_stats(
    float* __restrict__ AGG, float* __restrict__ stats, int n4)
{
    __shared__ float ls[128];
    const int t = threadIdx.x;
    if (t < 128) ls[t] = 0.f;
    __syncthreads();
    int idx = blockIdx.x * 256 + t;
    const int stride = gridDim.x * 256;
    const int f0 = (idx << 2) & 63;     // invariant: stride*4 % 64 == 0
    float s0=0,s1=0,s2=0,s3=0,q0=0,q1=0,q2=0,q3=0;
    for (; idx < n4; idx += stride) {
        float4 a = reinterpret_cast<float4*>(AGG)[idx];
        a.x = fmaxf(a.x, 0.f); a.y = fmaxf(a.y, 0.f);
        a.z = fmaxf(a.z, 0.f); a.w = fmaxf(a.w, 0.f);
        reinterpret_cast<float4*>(AGG)[idx] = a;
        s0 += a.x; q0 = fmaf(a.x, a.x, q0);
        s1 += a.y; q1 = fmaf(a.y, a.y, q1);
        s2 += a.z; q2 = fmaf(a.z, a.z, q2);
        s3 += a.w; q3 = fmaf(a.w, a.w, q3);
    }
    atomicAdd(&ls[f0],     s0); atomicAdd(&ls[f0 + 1],     s1);
    atomicAdd(&ls[f0 + 2], s2); atomicAdd(&ls[f0 + 3],     s3);
    atomicAdd(&ls[64 + f0],     q0); atomicAdd(&ls[64 + f0 + 1], q1);
    atomicAdd(&ls[64 + f0 + 2], q2); atomicAdd(&ls[64 + f0 + 3], q3);
    __syncthreads();
    if (t < 128) atomicAdd(&stats[t], ls[t]);
}

// ---------------- finalize: scale/shift; re-zero sums for next layer ----------------
__global__ void finalize_stats(float* __restrict__ stats,
                               const float* __restrict__ gamma,
                               const float* __restrict__ beta, int nrows)
{
    int t = threadIdx.x;  // 64 threads
    float invN = 1.0f / (float)nrows;
    float mean = stats[t] * invN;
    float var  = stats[64 + t] * invN - mean * mean;
    float sc   = gamma[t] * rsqrtf(var + BN_EPS);
    stats[128 + t] = sc;
    stats[192 + t] = beta[t] - mean * sc;
    stats[t] = 0.f;
    stats[64 + t] = 0.f;
}

// ---------------- apply (final layer): out = y*scale + shift ----------------
__global__ __launch_bounds__(256) void apply_bn(
    const float* __restrict__ AGG, const float* __restrict__ stats,
    float* __restrict__ xout, int ntot4)
{
    int idx = blockIdx.x * 256 + threadIdx.x;
    const int stride = gridDim.x * 256;
    const float4* st4 = reinterpret_cast<const float4*>(stats);
    for (; idx < ntot4; idx += stride) {
        float4 a = reinterpret_cast<const float4*>(AGG)[idx];
        int c4 = idx & 15;
        float4 sc = st4[32 + c4];
        float4 sh = st4[48 + c4];
        float4 o;
        o.x = a.x * sc.x + sh.x;
        o.y = a.y * sc.y + sh.y;
        o.z = a.z * sc.z + sh.z;
        o.w = a.w * sc.w + sh.w;
        reinterpret_cast<float4*>(xout)[idx] = o;
    }
}

extern "C" void kernel_launch(void* const* d_in, const int* in_sizes, int n_in,
                              void* d_out, int out_size, void* d_ws, size_t ws_size,
                              hipStream_t stream)
{
    const float* x     = (const float*)d_in[0];
    const int*   ei    = (const int*)d_in[1];
    const float* Wk    = (const float*)d_in[3];
    const float* bk    = (const float*)d_in[4];
    const float* Wq    = (const float*)d_in[5];
    const float* bq    = (const float*)d_in[6];
    const float* Wv    = (const float*)d_in[7];
    const float* bv    = (const float*)d_in[8];
    const float* Ws    = (const float*)d_in[9];
    const float* bs    = (const float*)d_in[10];
    const float* bias  = (const float*)d_in[11];
    const float* gamma = (const float*)d_in[12];
    const float* beta  = (const float*)d_in[13];

    const int nrows  = in_sizes[0] / D;     // 100000
    const int nedges = in_sizes[1] / 2;     // 1250000
    const int nm     = nrows * D;
    const int NCmax  = (nedges + nrows + CH - 1) / CH;

    float* out = (float*)d_out;
    float* ws  = (float*)d_ws;
    float* EK  = ws;                                     // nm f32
    unsigned int* QV = (unsigned int*)(EK + nm);         // nm + 64 u32 (incl. dummy row)
    float* AGG = (float*)(QV + nm + 64);                 // nm f32
    float* stats = AGG + nm;                             // 256 f32
    int* counts  = (int*)(stats + 256);                  // nrows
    int* offs    = counts + nrows;                       // nrows+1
    int* bsums   = offs + nrows + 1;                     // 512
    int* nstart_map = bsums + 512;                       // NCmax
    int* csr_src = nstart_map + NCmax;                   // nedges + nrows (padded)
    int* rank    = csr_src + nedges + nrows;             // nedges

    const int* srcI = ei;
    const int* dstI = ei + nedges;

    const int gemm_blocks = (nrows + 63) / 64;
    const int edge_blocks = (nedges + 255) / 256;
    const int node_blocks = (nrows + 255) / 256;         // 391 (<512 for scan2)
    const int agg_blocks  = (NCmax + 3) / 4;             // 1 wave per chunk

    // ---- CSR build (even-padded; identical for both layers) ----
    hipMemsetAsync(counts, 0, (size_t)nrows * sizeof(int), stream);
    hist_rank<<<edge_blocks, 256, 0, stream>>>(dstI, counts, rank, nedges);
    scan1<<<node_blocks, 256, 0, stream>>>(counts, offs, bsums, nrows);
    scan2<<<1, 512, 0, stream>>>(bsums, node_blocks);
    scan3<<<node_blocks, 256, 0, stream>>>(offs, bsums, counts, stats, QV, nrows);
    scatter_norank<<<edge_blocks, 256, 0, stream>>>(srcI, dstI, offs, rank, csr_src, nedges);
    pad_fill<<<node_blocks, 256, 0, stream>>>(counts, offs, csr_src, nrows);
    node_start_k<<<node_blocks, 256, 0, stream>>>(offs, nstart_map, nrows);

    // ---- layer 1 (variant A: 2 edges / load inst) ----
    gemm_fused<false><<<gemm_blocks, 256, 0, stream>>>(x,
        Wk, bk, Wq, bq, Wv, bv, Ws, bs, bias, stats, EK, QV, AGG, nrows);
    edge_agg<2><<<agg_blocks, 256, 0, stream>>>(csr_src, offs, nstart_map, EK, QV, AGG, nrows);
    relu_stats<<<1024, 256, 0, stream>>>(AGG, stats, nm / 4);
    finalize_stats<<<1, 64, 0, stream>>>(stats, gamma, beta, nrows);

    // ---- layer 2 (variant B: 1 edge / load inst; BN-apply fused into staging) ----
    gemm_fused<true><<<gemm_blocks, 256, 0, stream>>>(AGG,
        Wk + D * D, bk + D, Wq + D * D, bq + D, Wv + D * D, bv + D,
        Ws + D * D, bs + D, bias + D, stats, EK, QV, AGG, nrows);
    edge_agg<1><<<agg_blocks, 256, 0, stream>>>(csr_src, offs, nstart_map, EK, QV, AGG, nrows);
    relu_stats<<<1024, 256, 0, stream>>>(AGG, stats, nm / 4);
    finalize_stats<<<1, 64, 0, stream>>>(stats, gamma + D, beta + D, nrows);
    apply_bn<<<2048, 256, 0, stream>>>(AGG, stats, out, nm / 4);
}

// Round 6
// 360.327 us; speedup vs baseline: 1.3657x; 1.1753x over previous
//
#include <hip/hip_runtime.h>
#include <math.h>

#define D 64
#define BN_EPS 1e-5f
#define CH 160   // edges per chunk: even, multiple of 16

using short8 = __attribute__((ext_vector_type(8))) short;
using f32x4  = __attribute__((ext_vector_type(4))) float;

static __device__ __forceinline__ unsigned short f2bf(float f) {
    unsigned int u = __float_as_uint(f);
    unsigned int r = (u + 0x7fffu + ((u >> 16) & 1u)) >> 16;
    return (unsigned short)r;
}
static __device__ __forceinline__ float clamp60(float x) {
    return fminf(fmaxf(x, -60.f), 60.f);
}

// ---------------- weight prep: fragment-linear bf16 for mfma_f32_16x16x32_bf16 ----------------
// layout idx = ((((l*4+m)*4+nc)*2+kb)*64 + lane)*8 + i ; element W_m[l][k][n],
// k = kb*32 + (lane>>4)*8 + i, n = nc*16 + (lane&15).
__global__ __launch_bounds__(256) void prep_weights(
    const float* __restrict__ Wk, const float* __restrict__ Wq,
    const float* __restrict__ Wv, const float* __restrict__ Ws,
    unsigned short* __restrict__ Wfrag)
{
    int idx = blockIdx.x * 256 + threadIdx.x;      // 32768 total
    int i    = idx & 7;
    int lane = (idx >> 3) & 63;
    int kb   = (idx >> 9) & 1;
    int nc   = (idx >> 10) & 3;
    int m    = (idx >> 12) & 3;
    int l    = (idx >> 14) & 1;
    int k = kb * 32 + (lane >> 4) * 8 + i;
    int n = nc * 16 + (lane & 15);
    const float* W = (m == 0) ? Wk : (m == 1) ? Wq : (m == 2) ? Wv : Ws;
    Wfrag[idx] = f2bf(W[(size_t)l * 4096 + k * 64 + n]);
}

// ---------------- fused 4-GEMM via MFMA ----------------
// EK = exp(-clamp(x@Wk+bk)); QV = {bf16(v)<<16 | bf16(exp(-clamp(q)))}; AGG = x@Ws+bs+bias.
// APPLY_BN: input is raw layer-1 AGG; apply relu + BN (stats[128..255]) while staging.
template<bool APPLY_BN>
__global__ __launch_bounds__(256) void gemm_fused(
    const float* x,                       // may alias AGG (own rows only)
    const unsigned short* __restrict__ Wfrag,
    const float* __restrict__ bk, const float* __restrict__ bq,
    const float* __restrict__ bv, const float* __restrict__ bs,
    const float* __restrict__ bias, const float* __restrict__ stats,
    float* __restrict__ EK, unsigned int* __restrict__ QV,
    float* AGG, int nrows)
{
    __shared__ unsigned short xt[64 * 64];   // bf16 tile, XOR-swizzled 16B chunks
    const int t = threadIdx.x;
    const int row0 = blockIdx.x * 64;

    #pragma unroll
    for (int it = 0; it < 4; ++it) {
        int fidx = t + it * 256;             // [0,1024): row=fidx>>4, c4=fidx&15
        int r = fidx >> 4, c4 = fidx & 15;
        int grow = row0 + r;
        float4 v = make_float4(0.f, 0.f, 0.f, 0.f);
        if (grow < nrows)
            v = *reinterpret_cast<const float4*>(&x[(size_t)grow * D + c4 * 4]);
        if (APPLY_BN) {
            const float4* st4 = reinterpret_cast<const float4*>(stats);
            float4 sc = st4[32 + c4], sh = st4[48 + c4];
            v.x = fmaxf(v.x, 0.f) * sc.x + sh.x;
            v.y = fmaxf(v.y, 0.f) * sc.y + sh.y;
            v.z = fmaxf(v.z, 0.f) * sc.z + sh.z;
            v.w = fmaxf(v.w, 0.f) * sc.w + sh.w;
        }
        ushort4 b;
        b.x = f2bf(v.x); b.y = f2bf(v.y); b.z = f2bf(v.z); b.w = f2bf(v.w);
        int phys = (c4 >> 1) ^ (r & 7);      // 16B-chunk XOR swizzle
        *reinterpret_cast<ushort4*>(&xt[r * 64 + phys * 8 + (c4 & 1) * 4]) = b;
    }
    __syncthreads();

    const int w = t >> 6, lane = t & 63;
    const int rbase = w * 16;                // this wave's 16-row band

    short8 A[2];
    #pragma unroll
    for (int kb = 0; kb < 2; ++kb) {
        int r = rbase + (lane & 15);
        int c16 = (kb * 4 + (lane >> 4)) ^ (r & 7);
        A[kb] = *reinterpret_cast<const short8*>(&xt[r * 64 + c16 * 8]);
    }

    f32x4 acc[4][4];                          // [mat][nc]
    #pragma unroll
    for (int m = 0; m < 4; ++m)
        #pragma unroll
        for (int nc = 0; nc < 4; ++nc)
            acc[m][nc] = (f32x4){0.f, 0.f, 0.f, 0.f};

    #pragma unroll
    for (int nc = 0; nc < 4; ++nc) {
        #pragma unroll
        for (int m = 0; m < 4; ++m) {
            #pragma unroll
            for (int kb = 0; kb < 2; ++kb) {
                short8 B = *reinterpret_cast<const short8*>(
                    &Wfrag[((((m * 4 + nc) * 2 + kb) * 64) + lane) * 8]);
                acc[m][nc] = __builtin_amdgcn_mfma_f32_16x16x32_bf16(A[kb], B, acc[m][nc], 0, 0, 0);
            }
        }
    }

    // epilogue: C/D layout col=lane&15, row=(lane>>4)*4+reg [verified gfx950 mapping]
    const int crow = rbase + ((lane >> 4) << 2);
    #pragma unroll
    for (int nc = 0; nc < 4; ++nc) {
        int c = nc * 16 + (lane & 15);
        float bkc = bk[c], bqc = bq[c], bvc = bv[c], bsc = bs[c] + bias[c];
        #pragma unroll
        for (int reg = 0; reg < 4; ++reg) {
            int grow = row0 + crow + reg;
            if (grow < nrows) {
                size_t o = (size_t)grow * D + c;
                EK[o] = __expf(-clamp60(acc[0][nc][reg] + bkc));
                float eq = __expf(-clamp60(acc[1][nc][reg] + bqc));
                QV[o] = ((unsigned int)f2bf(acc[2][nc][reg] + bvc) << 16) | (unsigned int)f2bf(eq);
                AGG[o] = acc[3][nc][reg] + bsc;
            }
        }
    }
}

// ---------------- CSR build (degree padded to even) ----------------
__global__ __launch_bounds__(256) void hist_rank(const int* __restrict__ dst,
                                                 int* __restrict__ counts,
                                                 int* __restrict__ rank, int nedges)
{
    int i = blockIdx.x * 256 + threadIdx.x;
    if (i < nedges) {
        int r = atomicAdd(&counts[dst[i]], 1);
        rank[i] = r;
    }
}

__global__ __launch_bounds__(256) void scan1(const int* __restrict__ counts,
                                             int* __restrict__ offs,
                                             int* __restrict__ bsums, int n)
{
    __shared__ int tmp[256];
    const int t = threadIdx.x;
    const int i = blockIdx.x * 256 + t;
    int v = (i < n) ? ((counts[i] + 1) & ~1) : 0;   // padded-to-even degree
    tmp[t] = v;
    __syncthreads();
    for (int off = 1; off < 256; off <<= 1) {
        int add = (t >= off) ? tmp[t - off] : 0;
        __syncthreads();
        tmp[t] += add;
        __syncthreads();
    }
    if (i < n) offs[i] = tmp[t] - v;   // exclusive
    if (t == 255) bsums[blockIdx.x] = tmp[255];
}

__global__ __launch_bounds__(512) void scan2(int* __restrict__ bsums, int nb)
{
    __shared__ int tmp[512];
    const int t = threadIdx.x;
    int v = (t < nb) ? bsums[t] : 0;
    tmp[t] = v;
    __syncthreads();
    for (int off = 1; off < 512; off <<= 1) {
        int add = (t >= off) ? tmp[t - off] : 0;
        __syncthreads();
        tmp[t] += add;
        __syncthreads();
    }
    if (t < nb) bsums[t] = tmp[t] - v;
}

__global__ __launch_bounds__(256) void scan3(int* __restrict__ offs,
                                             const int* __restrict__ bsums,
                                             const int* __restrict__ counts,
                                             float* __restrict__ stats,
                                             unsigned int* __restrict__ QV, int n)
{
    int i = blockIdx.x * 256 + threadIdx.x;
    if (i < n) {
        int o = offs[i] + bsums[blockIdx.x];
        offs[i] = o;
        if (i == n - 1) offs[n] = o + ((counts[i] + 1) & ~1);  // padded total
    }
    if (i < 128) stats[i] = 0.f;                          // BN accumulators for layer 1
    if (i < 64)  QV[((size_t)n << 6) | i] = 0x00003F80u;  // dummy row: v=0, eq=1.0
}

__global__ __launch_bounds__(256) void scatter_norank(const int* __restrict__ src,
                                                      const int* __restrict__ dst,
                                                      const int* __restrict__ offs,
                                                      const int* __restrict__ rank,
                                                      int* __restrict__ csr_src, int nedges)
{
    int i = blockIdx.x * 256 + threadIdx.x;
    if (i < nedges) {
        int d = dst[i];
        csr_src[offs[d] + rank[i]] = src[i];
    }
}

// pad odd-degree nodes with dummy src + build chunk->first-node map (merged)
__global__ __launch_bounds__(256) void pad_nstart(const int* __restrict__ counts,
                                                  const int* __restrict__ offs,
                                                  int* __restrict__ csr_src,
                                                  int* __restrict__ node_start, int n)
{
    int i = blockIdx.x * 256 + threadIdx.x;
    if (i >= n) return;
    if (counts[i] & 1) csr_src[offs[i] + counts[i]] = n;
    int a = offs[i], b = offs[i + 1];
    if (a == b) return;
    for (int c = (a + CH - 1) / CH; c * CH < b; ++c) node_start[c] = i;
}

// ---------------- edge-parallel aggregation over CSR chunks ----------------
template<int EPI>
__global__ __launch_bounds__(256) void edge_agg(
    const int* __restrict__ csr_src, const int* __restrict__ offs,
    const int* __restrict__ node_start,
    const float* __restrict__ EK, const unsigned int* __restrict__ QV,
    float* __restrict__ AGG, int nnodes)
{
    const int lane  = threadIdx.x & 63;
    const int chunk = __builtin_amdgcn_readfirstlane((int)((blockIdx.x * 256 + threadIdx.x) >> 6));
    const int Epad  = offs[nnodes];
    const int e0 = chunk * CH;
    if (e0 >= Epad) return;
    const int e1 = min(e0 + CH, Epad);

    int n      = node_start[chunk];
    int nstart = offs[n];
    int nend   = offs[n + 1];

    float accx = 0.f, accy = 0.f;
    float ekx = 0.f, eky = 0.f;
    if (EPI == 2) {
        float2 ekv = reinterpret_cast<const float2*>(EK)[((size_t)n << 5) | (lane & 31)];
        ekx = ekv.x; eky = ekv.y;
    } else {
        ekx = EK[((size_t)n << 6) | lane];
    }

    auto flush = [&](bool partial) {
        if (EPI == 2) {
            float tx = accx + __shfl_xor(accx, 32);
            float ty = accy + __shfl_xor(accy, 32);
            if (lane < 32) {
                int base = (n << 6) + (lane << 1);
                if (partial) {
                    atomicAdd(&AGG[base], tx);
                    atomicAdd(&AGG[base + 1], ty);
                } else {
                    float2* r = reinterpret_cast<float2*>(&AGG[base]);
                    float2 cur = *r;
                    cur.x += tx; cur.y += ty;
                    *r = cur;
                }
            }
        } else {
            int idx = (n << 6) | lane;
            if (partial) atomicAdd(&AGG[idx], accx);
            else         AGG[idx] += accx;
        }
    };
    auto advance = [&](int eidx) {
        do { ++n; } while (offs[n + 1] == eidx);   // skip empty nodes
        nstart = eidx;
        nend   = offs[n + 1];
        accx = 0.f; accy = 0.f;
        if (EPI == 2) {
            float2 ekv = reinterpret_cast<const float2*>(EK)[((size_t)n << 5) | (lane & 31)];
            ekx = ekv.x; eky = ekv.y;
        } else {
            ekx = EK[((size_t)n << 6) | lane];
        }
    };

    for (int e = e0; e < e1; e += 64) {
        const int cnt = min(64, e1 - e);
        int sAll = (lane < cnt) ? csr_src[e + lane] : nnodes;
        for (int b = 0; b < cnt; b += 16) {
            const int bc = min(16, cnt - b);
            if (EPI == 1) {
                unsigned int p[16];
                #pragma unroll
                for (int u = 0; u < 16; ++u) {
                    if (u < bc) {
                        int s = __shfl(sAll, b + u);
                        p[u] = QV[((size_t)s << 6) | lane];
                    }
                }
                #pragma unroll
                for (int u = 0; u < 16; ++u) {
                    if (u < bc) {
                        int eidx = e + b + u;
                        if (eidx == nend) { flush(nstart < e0); advance(eidx); }
                        float eq = __uint_as_float(p[u] << 16);
                        float vv = __uint_as_float(p[u] & 0xffff0000u);
                        float g  = __builtin_amdgcn_rcpf(fmaf(ekx, eq, 1.0f));
                        accx = fmaf(g, vv, accx);
                    }
                }
            } else {
                unsigned long long p[8];
                const int half = lane >> 5;
                #pragma unroll
                for (int u = 0; u < 8; ++u) {
                    if (2 * u < bc) {
                        int s = __shfl(sAll, b + 2 * u + half);
                        p[u] = reinterpret_cast<const unsigned long long*>(QV)[((size_t)s << 5) | (lane & 31)];
                    }
                }
                #pragma unroll
                for (int u = 0; u < 8; ++u) {
                    if (2 * u < bc) {
                        int eidx = e + b + 2 * u;
                        if (eidx == nend) { flush(nstart < e0); advance(eidx); }
                        unsigned int lo = (unsigned int)p[u];
                        unsigned int hi = (unsigned int)(p[u] >> 32);
                        float eq0 = __uint_as_float(lo << 16);
                        float v0  = __uint_as_float(lo & 0xffff0000u);
                        float eq1 = __uint_as_float(hi << 16);
                        float v1  = __uint_as_float(hi & 0xffff0000u);
                        float g0  = __builtin_amdgcn_rcpf(fmaf(ekx, eq0, 1.0f));
                        float g1  = __builtin_amdgcn_rcpf(fmaf(eky, eq1, 1.0f));
                        accx = fmaf(g0, v0, accx);
                        accy = fmaf(g1, v1, accy);
                    }
                }
            }
        }
    }
    flush((nstart < e0) || (nend > e1));
}

// ---------------- per-feature BN stats of relu(AGG) (no write-back) ----------------
__global__ __launch_bounds__(256) void relu_stats(
    const float* __restrict__ AGG, float* __restrict__ stats, int n4)
{
    __shared__ float ls[128];
    const int t = threadIdx.x;
    if (t < 128) ls[t] = 0.f;
    __syncthreads();
    int idx = blockIdx.x * 256 + t;
    const int stride = gridDim.x * 256;
    const int f0 = (idx << 2) & 63;     // invariant: stride*4 % 64 == 0
    float s0=0,s1=0,s2=0,s3=0,q0=0,q1=0,q2=0,q3=0;
    for (; idx < n4; idx += stride) {
        float4 a = reinterpret_cast<const float4*>(AGG)[idx];
        a.x = fmaxf(a.x, 0.f); a.y = fmaxf(a.y, 0.f);
        a.z = fmaxf(a.z, 0.f); a.w = fmaxf(a.w, 0.f);
        s0 += a.x; q0 = fmaf(a.x, a.x, q0);
        s1 += a.y; q1 = fmaf(a.y, a.y, q1);
        s2 += a.z; q2 = fmaf(a.z, a.z, q2);
        s3 += a.w; q3 = fmaf(a.w, a.w, q3);
    }
    atomicAdd(&ls[f0],     s0); atomicAdd(&ls[f0 + 1],     s1);
    atomicAdd(&ls[f0 + 2], s2); atomicAdd(&ls[f0 + 3],     s3);
    atomicAdd(&ls[64 + f0],     q0); atomicAdd(&ls[64 + f0 + 1], q1);
    atomicAdd(&ls[64 + f0 + 2], q2); atomicAdd(&ls[64 + f0 + 3], q3);
    __syncthreads();
    if (t < 128) atomicAdd(&stats[t], ls[t]);
}

// ---------------- finalize: scale/shift; re-zero sums for next layer ----------------
__global__ void finalize_stats(float* __restrict__ stats,
                               const float* __restrict__ gamma,
                               const float* __restrict__ beta, int nrows)
{
    int t = threadIdx.x;  // 64 threads
    float invN = 1.0f / (float)nrows;
    float mean = stats[t] * invN;
    float var  = stats[64 + t] * invN - mean * mean;
    float sc   = gamma[t] * rsqrtf(var + BN_EPS);
    stats[128 + t] = sc;
    stats[192 + t] = beta[t] - mean * sc;
    stats[t] = 0.f;
    stats[64 + t] = 0.f;
}

// ---------------- apply (final layer): out = relu(AGG)*scale + shift ----------------
__global__ __launch_bounds__(256) void apply_bn(
    const float* __restrict__ AGG, const float* __restrict__ stats,
    float* __restrict__ xout, int ntot4)
{
    int idx = blockIdx.x * 256 + threadIdx.x;
    const int stride = gridDim.x * 256;
    const float4* st4 = reinterpret_cast<const float4*>(stats);
    for (; idx < ntot4; idx += stride) {
        float4 a = reinterpret_cast<const float4*>(AGG)[idx];
        int c4 = idx & 15;
        float4 sc = st4[32 + c4];
        float4 sh = st4[48 + c4];
        float4 o;
        o.x = fmaxf(a.x, 0.f) * sc.x + sh.x;
        o.y = fmaxf(a.y, 0.f) * sc.y + sh.y;
        o.z = fmaxf(a.z, 0.f) * sc.z + sh.z;
        o.w = fmaxf(a.w, 0.f) * sc.w + sh.w;
        reinterpret_cast<float4*>(xout)[idx] = o;
    }
}

extern "C" void kernel_launch(void* const* d_in, const int* in_sizes, int n_in,
                              void* d_out, int out_size, void* d_ws, size_t ws_size,
                              hipStream_t stream)
{
    const float* x     = (const float*)d_in[0];
    const int*   ei    = (const int*)d_in[1];
    const float* Wk    = (const float*)d_in[3];
    const float* bk    = (const float*)d_in[4];
    const float* Wq    = (const float*)d_in[5];
    const float* bq    = (const float*)d_in[6];
    const float* Wv    = (const float*)d_in[7];
    const float* bv    = (const float*)d_in[8];
    const float* Ws    = (const float*)d_in[9];
    const float* bs    = (const float*)d_in[10];
    const float* bias  = (const float*)d_in[11];
    const float* gamma = (const float*)d_in[12];
    const float* beta  = (const float*)d_in[13];

    const int nrows  = in_sizes[0] / D;     // 100000
    const int nedges = in_sizes[1] / 2;     // 1250000
    const int nm     = nrows * D;
    const int NCmax  = (nedges + nrows + CH - 1) / CH;

    float* out = (float*)d_out;
    float* ws  = (float*)d_ws;
    float* EK  = ws;                                     // nm f32
    unsigned int* QV = (unsigned int*)(EK + nm);         // nm + 64 u32 (incl. dummy row)
    float* AGG = (float*)(QV + nm + 64);                 // nm f32
    float* stats = AGG + nm;                             // 256 f32
    int* counts  = (int*)(stats + 256);                  // nrows
    int* offs    = counts + nrows;                       // nrows+1
    int* bsums   = offs + nrows + 1;                     // 512
    int* nstart_map = bsums + 512;                       // NCmax
    int* csr_src = nstart_map + NCmax;                   // nedges + nrows (padded)
    int* rank    = csr_src + nedges + nrows;             // nedges
    unsigned short* Wfrag = (unsigned short*)(rank + nedges);  // 32768 u16

    const int* srcI = ei;
    const int* dstI = ei + nedges;

    const int gemm_blocks = (nrows + 63) / 64;
    const int edge_blocks = (nedges + 255) / 256;
    const int node_blocks = (nrows + 255) / 256;         // 391 (<512 for scan2)
    const int agg_blocks  = (NCmax + 3) / 4;             // 1 wave per chunk

    // ---- weight prep + CSR build (edge_index identical for both layers) ----
    prep_weights<<<128, 256, 0, stream>>>(Wk, Wq, Wv, Ws, Wfrag);
    hipMemsetAsync(counts, 0, (size_t)nrows * sizeof(int), stream);
    hist_rank<<<edge_blocks, 256, 0, stream>>>(dstI, counts, rank, nedges);
    scan1<<<node_blocks, 256, 0, stream>>>(counts, offs, bsums, nrows);
    scan2<<<1, 512, 0, stream>>>(bsums, node_blocks);
    scan3<<<node_blocks, 256, 0, stream>>>(offs, bsums, counts, stats, QV, nrows);
    scatter_norank<<<edge_blocks, 256, 0, stream>>>(srcI, dstI, offs, rank, csr_src, nedges);
    pad_nstart<<<node_blocks, 256, 0, stream>>>(counts, offs, csr_src, nstart_map, nrows);

    // ---- layer 1 ----
    gemm_fused<false><<<gemm_blocks, 256, 0, stream>>>(x, Wfrag,
        bk, bq, bv, bs, bias, stats, EK, QV, AGG, nrows);
    edge_agg<2><<<agg_blocks, 256, 0, stream>>>(csr_src, offs, nstart_map, EK, QV, AGG, nrows);
    relu_stats<<<1024, 256, 0, stream>>>(AGG, stats, nm / 4);
    finalize_stats<<<1, 64, 0, stream>>>(stats, gamma, beta, nrows);

    // ---- layer 2 (relu+BN of layer 1 fused into MFMA staging) ----
    gemm_fused<true><<<gemm_blocks, 256, 0, stream>>>(AGG, Wfrag + 16384,
        bk + D, bq + D, bv + D, bs + D, bias + D, stats, EK, QV, AGG, nrows);
    edge_agg<1><<<agg_blocks, 256, 0, stream>>>(csr_src, offs, nstart_map, EK, QV, AGG, nrows);
    relu_stats<<<1024, 256, 0, stream>>>(AGG, stats, nm / 4);
    finalize_stats<<<1, 64, 0, stream>>>(stats, gamma + D, beta + D, nrows);
    apply_bn<<<2048, 256, 0, stream>>>(AGG, stats, out, nm / 4);
}